// Round 8
// baseline (469.089 us; speedup 1.0000x reference)
//
#include <hip/hip_runtime.h>
#include <math.h>

#define B_    16
#define C_    256
#define H_    200
#define W_    200
#define NBOX  100
#define HID   256
#define OUTK  7
#define ROI_DIM 12544        // C_ * 49
#define KP    37632          // 3 * ROI_DIM  (split-bf16 interleave: [ah,ah,al]x[bh,bl,bh])
#define NCLS  4

struct __attribute__((packed, aligned(4))) f2u { float x, y; };

typedef __attribute__((ext_vector_type(8))) short short8v;
typedef __attribute__((ext_vector_type(4))) float f32x4;

static __device__ __forceinline__ unsigned short f2bf(float f) {
  unsigned u = __float_as_uint(f);
  return (unsigned short)((u + 0x7FFFu + ((u >> 16) & 1u)) >> 16);   // RNE
}
static __device__ __forceinline__ float bf2f(unsigned short h) {
  return __uint_as_float(((unsigned)h) << 16);
}

static __device__ __forceinline__ void gload_lds16(const void* g, void* l) {
  __builtin_amdgcn_global_load_lds(
      (const __attribute__((address_space(1))) unsigned*)g,
      (__attribute__((address_space(3))) unsigned*)l, 16, 0, 0);
}

// ---------------------------------------------------------------- K1: ROI align — wide LDS-DMA, half-channel phases, 1-wave blocks
// Block = 1 wave = (box, 8-channel group); 16 phases: (channel, half).
// Half A = rows 0..15 (bins 0-3), half B = rows 16..27 (bins 4-6).
// Each phase staged by 4-5 global_load_lds width-16 instrs (64 lanes x 16B;
// per-lane src = precomputed (row, 4-col group), LDS dest linear lane*16).
// Double-buffered with counted vmcnt; reads fenced by lgkmcnt(0)+sched_barrier
// before the overwriting DMA issue. ~9 KB LDS -> 16 blocks/CU.
__global__ __launch_bounds__(64) void roi_pool_kernel(
    const float* __restrict__ feat, const float* __restrict__ boxes,
    unsigned short* __restrict__ Ap)
{
  __shared__ float tile[2][1088];      // 2 x 4352 B (16 rows x 68 cols)
  __shared__ int   rowoff_s[28];
  __shared__ int   ixs_s[14];
  __shared__ float flys_s[14], flxs_s[14];

  int raw = blockIdx.x;
  int g   = raw & 31;           // channel group [g*8, g*8+8); g%8 == XCD slot
  int bn  = raw >> 5;
  int b   = bn / NBOX;

  const float* bx = boxes + (size_t)bn * 4;
  float px1 = bx[0] - 0.5f, py1 = bx[1] - 0.5f;
  float px2 = bx[2] - 0.5f, py2 = bx[3] - 0.5f;
  float bh = (py2 - py1) * (1.0f / OUTK);
  float bw = (px2 - px1) * (1.0f / OUTK);

  int lane = threadIdx.x;
  if (lane < 14) {
    int i = lane >> 1, s = lane & 1;
    float yy = py1 + ((float)i + ((float)s + 0.5f) * 0.5f) * bh;
    float yc = fminf(fmaxf(yy, 0.0f), (float)(H_ - 1));
    int y0 = min((int)floorf(yc), H_ - 2);
    rowoff_s[2 * lane]     = y0 * W_;
    rowoff_s[2 * lane + 1] = y0 * W_ + W_;
    flys_s[lane] = yc - (float)y0;
  } else if (lane >= 16 && lane < 30) {
    int t = lane - 16;
    int j = t >> 1, s = t & 1;
    float xx = px1 + ((float)j + ((float)s + 0.5f) * 0.5f) * bw;
    float xc = fminf(fmaxf(xx, 0.0f), (float)(W_ - 1));
    int x0 = min((int)floorf(xc), W_ - 2);
    ixs_s[t]  = x0;
    flxs_s[t] = xc - (float)x0;
  }
  asm volatile("s_waitcnt lgkmcnt(0)" ::: "memory");

  int xlo4 = ixs_s[0] & ~3;            // 16B-aligned window start

  // per-lane DMA source offsets (floats): slot s=k*64+lane -> (row=s/17, 4-col group)
  int offA[5], offB[4];
  #pragma unroll
  for (int k = 0; k < 5; ++k) {
    int s = k * 64 + lane;
    int r = s / 17;
    int xo = (s - r * 17) * 4;
    offA[k] = rowoff_s[min(r, 15)] + min(xlo4 + xo, W_ - 4);
  }
  #pragma unroll
  for (int k = 0; k < 4; ++k) {
    int s = k * 64 + lane;
    int r = s / 17;
    int xo = (s - r * 17) * 4;
    offB[k] = rowoff_s[16 + min(r, 11)] + min(xlo4 + xo, W_ - 4);
  }
  bool actA4 = lane < 16;              // slots 256..271
  bool actB3 = lane < 12;              // slots 192..203

  // per-lane bin constants, half A (bins 0-3, 28 lanes)
  int lA = lane < 28 ? lane : 0;
  int biA = lA / 7, bjA = lA - biA * 7;
  float lyA0 = flys_s[2*biA],   hyA0 = 1.0f - lyA0;
  float lyA1 = flys_s[2*biA+1], hyA1 = 1.0f - lyA1;
  float lxA0 = flxs_s[2*bjA],   hxA0 = 1.0f - lxA0;
  float lxA1 = flxs_s[2*bjA+1], hxA1 = 1.0f - lxA1;
  int xoA0 = ixs_s[2*bjA] - xlo4, xoA1 = ixs_s[2*bjA+1] - xlo4;
  int baA  = biA * (4 * 68);
  // half B (bins 4-6, 21 lanes); buffer rows = global rows - 16
  int lB = lane < 21 ? lane : 0;
  int biB = lB / 7, bjB = lB - biB * 7;        // global bin = 4 + biB
  float lyB0 = flys_s[2*(biB+4)],   hyB0 = 1.0f - lyB0;
  float lyB1 = flys_s[2*(biB+4)+1], hyB1 = 1.0f - lyB1;
  float lxB0 = flxs_s[2*bjB],   hxB0 = 1.0f - lxB0;
  float lxB1 = flxs_s[2*bjB+1], hxB1 = 1.0f - lxB1;
  int xoB0 = ixs_s[2*bjB] - xlo4, xoB1 = ixs_s[2*bjB+1] - xlo4;
  int baB  = biB * (4 * 68);

  int c0 = g * 8;
  const char* fc = (const char*)(feat + (size_t)b * (C_ * H_ * W_) + (size_t)c0 * (H_ * W_));
  unsigned short* pwb = Ap + (size_t)bn * KP + (size_t)c0 * 49 * 3;

  auto issueA = [&](int n, float* buf) {
    const char* cb = fc + (size_t)n * (H_ * W_ * 4);
    gload_lds16(cb + (size_t)offA[0] * 4, buf + 0 * 256);
    gload_lds16(cb + (size_t)offA[1] * 4, buf + 1 * 256);
    gload_lds16(cb + (size_t)offA[2] * 4, buf + 2 * 256);
    gload_lds16(cb + (size_t)offA[3] * 4, buf + 3 * 256);
    if (actA4) gload_lds16(cb + (size_t)offA[4] * 4, buf + 4 * 256);
  };
  auto issueB = [&](int n, float* buf) {
    const char* cb = fc + (size_t)n * (H_ * W_ * 4);
    gload_lds16(cb + (size_t)offB[0] * 4, buf + 0 * 256);
    gload_lds16(cb + (size_t)offB[1] * 4, buf + 1 * 256);
    gload_lds16(cb + (size_t)offB[2] * 4, buf + 2 * 256);
    if (actB3) gload_lds16(cb + (size_t)offB[3] * 4, buf + 3 * 256);
  };

  issueA(0, tile[0]);                  // prologue: half A of channel 0

  #pragma unroll 1
  for (int n = 0; n < 8; ++n) {
    // ---- half A of channel n (tile[0])
    issueB(n, tile[1]);
    asm volatile("s_waitcnt vmcnt(4)" ::: "memory");   // A(n) landed (4 B-loads in flight)
    __builtin_amdgcn_sched_barrier(0);
    f2u a0, a1, b0, b1, c2, c3, d2, d3;
    {
      const float* T = tile[0] + baA;
      a0 = *(const f2u*)(T + 0 * 68 + xoA0);
      a1 = *(const f2u*)(T + 1 * 68 + xoA0);
      b0 = *(const f2u*)(T + 0 * 68 + xoA1);
      b1 = *(const f2u*)(T + 1 * 68 + xoA1);
      c2 = *(const f2u*)(T + 2 * 68 + xoA0);
      c3 = *(const f2u*)(T + 3 * 68 + xoA0);
      d2 = *(const f2u*)(T + 2 * 68 + xoA1);
      d3 = *(const f2u*)(T + 3 * 68 + xoA1);
    }
    asm volatile("s_waitcnt lgkmcnt(0)" ::: "memory");  // reads in regs before t0 reuse
    __builtin_amdgcn_sched_barrier(0);
    if (n < 7) issueA(n + 1, tile[0]);
    {
      float sum = hyA0 * (hxA0 * a0.x + lxA0 * a0.y) + lyA0 * (hxA0 * a1.x + lxA0 * a1.y)
                + hyA0 * (hxA1 * b0.x + lxA1 * b0.y) + lyA0 * (hxA1 * b1.x + lxA1 * b1.y)
                + hyA1 * (hxA0 * c2.x + lxA0 * c2.y) + lyA1 * (hxA0 * c3.x + lxA0 * c3.y)
                + hyA1 * (hxA1 * d2.x + lxA1 * d2.y) + lyA1 * (hxA1 * d3.x + lxA1 * d3.y);
      if (lane < 28) {
        float s = sum * 0.25f;
        unsigned short hi = f2bf(s);
        unsigned short lo = f2bf(s - bf2f(hi));
        unsigned short* pw = pwb + (size_t)(n * 49 + lane) * 3;
        pw[0] = hi; pw[1] = hi; pw[2] = lo;
      }
    }
    // ---- half B of channel n (tile[1])
    if (n < 7) asm volatile("s_waitcnt vmcnt(5)" ::: "memory");  // B(n) landed
    else       asm volatile("s_waitcnt vmcnt(0)" ::: "memory");
    __builtin_amdgcn_sched_barrier(0);
    {
      const float* T = tile[1] + baB;
      a0 = *(const f2u*)(T + 0 * 68 + xoB0);
      a1 = *(const f2u*)(T + 1 * 68 + xoB0);
      b0 = *(const f2u*)(T + 0 * 68 + xoB1);
      b1 = *(const f2u*)(T + 1 * 68 + xoB1);
      c2 = *(const f2u*)(T + 2 * 68 + xoB0);
      c3 = *(const f2u*)(T + 3 * 68 + xoB0);
      d2 = *(const f2u*)(T + 2 * 68 + xoB1);
      d3 = *(const f2u*)(T + 3 * 68 + xoB1);
    }
    asm volatile("s_waitcnt lgkmcnt(0)" ::: "memory");
    __builtin_amdgcn_sched_barrier(0);
    {
      float sum = hyB0 * (hxB0 * a0.x + lxB0 * a0.y) + lyB0 * (hxB0 * a1.x + lxB0 * a1.y)
                + hyB0 * (hxB1 * b0.x + lxB1 * b0.y) + lyB0 * (hxB1 * b1.x + lxB1 * b1.y)
                + hyB1 * (hxB0 * c2.x + lxB0 * c2.y) + lyB1 * (hxB0 * c3.x + lxB0 * c3.y)
                + hyB1 * (hxB1 * d2.x + lxB1 * d2.y) + lyB1 * (hxB1 * d3.x + lxB1 * d3.y);
      if (lane < 21) {
        float s = sum * 0.25f;
        unsigned short hi = f2bf(s);
        unsigned short lo = f2bf(s - bf2f(hi));
        unsigned short* pw = pwb + (size_t)(n * 49 + 28 + lane) * 3;
        pw[0] = hi; pw[1] = hi; pw[2] = lo;
      }
    }
  }
}

// ---------------------------------------------------------------- K1b: w_roi -> split-bf16 B' [bh, bl, bh]
__global__ __launch_bounds__(256) void wconv_kernel(
    const float* __restrict__ w, unsigned short* __restrict__ Bp)
{
  int i = blockIdx.x * 256 + threadIdx.x;     // over 256*12544
  int n = i / ROI_DIM, k = i - n * ROI_DIM;
  float f = w[i];
  unsigned short hi = f2bf(f);
  unsigned short lo = f2bf(f - bf2f(hi));
  unsigned short* r = Bp + (size_t)n * KP + 3 * k;
  r[0] = hi; r[1] = lo; r[2] = hi;
}

// ---------------------------------------------------------------- K2: token init (bias)
__global__ __launch_bounds__(256) void token_init_kernel(
    const float* __restrict__ b_roi, float* __restrict__ tokens)
{
  int i = blockIdx.x * 256 + threadIdx.x;   // 409600 total
  tokens[i] = b_roi[i & 255];
}

// ---------------------------------------------------------------- K3: bf16 MFMA GEMM  tokens += A'(1600xKP) @ B'(256xKP)^T
#define GBM 64
#define GBN 128
#define GBK 64
#define KSP 28
#define KT  21        // (KP/GBK)/KSP = 588/28
__global__ __launch_bounds__(256) void gemm_kernel(
    const unsigned short* __restrict__ Ap,
    const unsigned short* __restrict__ Bp,
    float* __restrict__ Cc)
{
  __shared__ __align__(16) short As[GBM * GBK];   // [row][8 chunks x 8 bf16], swizzled
  __shared__ __align__(16) short Bs[GBN * GBK];

  int tid  = threadIdx.x;
  int lane = tid & 63;
  int w    = tid >> 6;
  int wr   = w >> 1, wc = w & 1;          // wave (wr,wc): rows wr*32, cols wc*64
  int m0 = blockIdx.x * GBM;
  int n0 = blockIdx.y * GBN;
  int kbase = blockIdx.z * (GBK * KT);

  f32x4 acc[2][4];
  #pragma unroll
  for (int mi = 0; mi < 2; ++mi)
    #pragma unroll
    for (int nj = 0; nj < 4; ++nj)
      acc[mi][nj] = (f32x4){0.f, 0.f, 0.f, 0.f};

  for (int kt = 0; kt < KT; ++kt) {
    int kg = kbase + kt * GBK;
    __syncthreads();                       // previous compute done before overwrite
    #pragma unroll
    for (int r = 0; r < 2; ++r) {          // stage A: 512 chunks of 16B
      int q = tid + r * 256;
      int row = q >> 3, c16 = q & 7;
      int kc16 = c16 ^ (row & 7);
      short8v v = *(const short8v*)(Ap + (size_t)(m0 + row) * KP + kg + kc16 * 8);
      *(short8v*)(As + row * GBK + c16 * 8) = v;
    }
    #pragma unroll
    for (int r = 0; r < 4; ++r) {          // stage B: 1024 chunks
      int q = tid + r * 256;
      int row = q >> 3, c16 = q & 7;
      int kc16 = c16 ^ (row & 7);
      short8v v = *(const short8v*)(Bp + (size_t)(n0 + row) * KP + kg + kc16 * 8);
      *(short8v*)(Bs + row * GBK + c16 * 8) = v;
    }
    __syncthreads();
    #pragma unroll
    for (int kk = 0; kk < 2; ++kk) {       // two K=32 steps per tile
      short8v af[2], bf[4];
      #pragma unroll
      for (int mi = 0; mi < 2; ++mi) {
        int row = wr * 32 + mi * 16 + (lane & 15);
        int c16 = (kk * 4 + (lane >> 4)) ^ (row & 7);
        af[mi] = *(const short8v*)(As + row * GBK + c16 * 8);
      }
      #pragma unroll
      for (int nj = 0; nj < 4; ++nj) {
        int row = wc * 64 + nj * 16 + (lane & 15);
        int c16 = (kk * 4 + (lane >> 4)) ^ (row & 7);
        bf[nj] = *(const short8v*)(Bs + row * GBK + c16 * 8);
      }
      #pragma unroll
      for (int mi = 0; mi < 2; ++mi)
        #pragma unroll
        for (int nj = 0; nj < 4; ++nj)
          acc[mi][nj] = __builtin_amdgcn_mfma_f32_16x16x32_bf16(
              af[mi], bf[nj], acc[mi][nj], 0, 0, 0);
    }
  }
  // epilogue: D col = lane&15, row = (lane>>4)*4 + reg
  int cn = lane & 15, rg = lane >> 4;
  #pragma unroll
  for (int mi = 0; mi < 2; ++mi)
    #pragma unroll
    for (int nj = 0; nj < 4; ++nj)
      #pragma unroll
      for (int r = 0; r < 4; ++r) {
        int row = m0 + wr * 32 + mi * 16 + rg * 4 + r;
        int col = n0 + wc * 64 + nj * 16 + cn;
        atomicAdd(&Cc[(size_t)row * HID + col], acc[mi][nj][r]);
      }
}

// ---------------------------------------------------------------- K4: attention + LN + MLP (one block per batch)
__global__ __launch_bounds__(256) void head_kernel(
    const float* __restrict__ tokens, const float* __restrict__ sev_q,
    const float* __restrict__ w_in,  const float* __restrict__ b_in,
    const float* __restrict__ w_out, const float* __restrict__ b_out,
    const float* __restrict__ ln_g,  const float* __restrict__ ln_b,
    const float* __restrict__ w1,    const float* __restrict__ b1,
    const float* __restrict__ w2,    const float* __restrict__ b2,
    float* __restrict__ outp)
{
  __shared__ float qh_s[256], qkv_s[1024], qkb_s[4];
  __shared__ float sc_s[400], att_s[400], tbar_s[1024];
  __shared__ float ctx_s[256], o_s[256], x_s[256], h1_s[256], red_s[8];
  int b = blockIdx.x, tid = threadIdx.x;
  const float* tok = tokens + (size_t)b * NBOX * HID;

  {
    const float* wq = w_in + (size_t)tid * HID;
    float a = 0.0f;
    for (int e = 0; e < HID; ++e) a += sev_q[e] * wq[e];
    qh_s[tid] = a + b_in[tid];
  }
  __syncthreads();
  if (tid < 4) {
    float a = 0.0f;
    for (int d = 0; d < 64; ++d) a += qh_s[tid * 64 + d] * b_in[256 + tid * 64 + d];
    qkb_s[tid] = a;
  }
  #pragma unroll
  for (int r = 0; r < 4; ++r) {
    int p = tid + r * 256;
    int h = p >> 8, e = p & 255;
    float a = 0.0f;
    for (int d = 0; d < 64; ++d)
      a += qh_s[h * 64 + d] * w_in[(size_t)(256 + h * 64 + d) * HID + e];
    qkv_s[p] = a;
  }
  __syncthreads();
  for (int p = tid; p < 4 * NBOX; p += 256) {
    int h = p / NBOX, t = p - h * NBOX;
    const float* tr = tok + (size_t)t * HID;
    const float* qv = qkv_s + h * 256;
    float a = 0.0f;
    for (int e = 0; e < HID; ++e) a += qv[e] * tr[e];
    sc_s[p] = (a + qkb_s[h]) * 0.125f;
  }
  __syncthreads();
  if (tid < 4) {
    float mx = -1e30f;
    for (int t = 0; t < NBOX; ++t) mx = fmaxf(mx, sc_s[tid * NBOX + t]);
    float sm = 0.0f;
    for (int t = 0; t < NBOX; ++t) {
      float e = expf(sc_s[tid * NBOX + t] - mx);
      att_s[tid * NBOX + t] = e; sm += e;
    }
    float inv = 1.0f / sm;
    for (int t = 0; t < NBOX; ++t) att_s[tid * NBOX + t] *= inv;
  }
  __syncthreads();
  #pragma unroll
  for (int r = 0; r < 4; ++r) {
    int p = tid + r * 256;
    int h = p >> 8, e = p & 255;
    float a = 0.0f;
    for (int t = 0; t < NBOX; ++t) a += att_s[h * NBOX + t] * tok[(size_t)t * HID + e];
    tbar_s[p] = a;
  }
  __syncthreads();
  {
    int h = tid >> 6;
    const float* wv = w_in + (size_t)(512 + tid) * HID;
    const float* tb = tbar_s + h * 256;
    float a = 0.0f;
    for (int e = 0; e < HID; ++e) a += tb[e] * wv[e];
    ctx_s[tid] = a + b_in[512 + tid];
  }
  __syncthreads();
  {
    const float* wo = w_out + (size_t)tid * HID;
    float a = 0.0f;
    for (int k = 0; k < HID; ++k) a += ctx_s[k] * wo[k];
    o_s[tid] = a + b_out[tid];
  }
  __syncthreads();
  {
    float v = o_s[tid];
    float s1 = v, s2 = v * v;
    #pragma unroll
    for (int off = 32; off > 0; off >>= 1) {
      s1 += __shfl_down(s1, off);
      s2 += __shfl_down(s2, off);
    }
    if ((tid & 63) == 0) { red_s[(tid >> 6) * 2] = s1; red_s[(tid >> 6) * 2 + 1] = s2; }
    __syncthreads();
    float sum = red_s[0] + red_s[2] + red_s[4] + red_s[6];
    float ssq = red_s[1] + red_s[3] + red_s[5] + red_s[7];
    float mu  = sum * (1.0f / 256.0f);
    float var = ssq * (1.0f / 256.0f) - mu * mu;
    float inv = rsqrtf(var + 1e-5f);
    x_s[tid] = (v - mu) * inv * ln_g[tid] + ln_b[tid];
  }
  __syncthreads();
  {
    const float* wr = w1 + (size_t)tid * HID;
    float a = 0.0f;
    for (int k = 0; k < HID; ++k) a += x_s[k] * wr[k];
    h1_s[tid] = fmaxf(a + b1[tid], 0.0f);
  }
  __syncthreads();
  if (tid < NCLS) {
    const float* wr = w2 + (size_t)tid * HID;
    float a = 0.0f;
    for (int k = 0; k < HID; ++k) a += h1_s[k] * wr[k];
    outp[b * NCLS + tid] = a + b2[tid];
  }
}

// ---------------------------------------------------------------- launch
extern "C" void kernel_launch(void* const* d_in, const int* in_sizes, int n_in,
                              void* d_out, int out_size, void* d_ws, size_t ws_size,
                              hipStream_t stream) {
  (void)in_sizes; (void)n_in; (void)out_size; (void)ws_size;
  const float* feat  = (const float*)d_in[0];
  const float* boxes = (const float*)d_in[1];
  const float* w_roi = (const float*)d_in[2];
  const float* b_roi = (const float*)d_in[3];
  const float* sev_q = (const float*)d_in[4];
  const float* w_in  = (const float*)d_in[5];
  const float* b_in  = (const float*)d_in[6];
  const float* w_out = (const float*)d_in[7];
  const float* b_out = (const float*)d_in[8];
  const float* ln_g  = (const float*)d_in[9];
  const float* ln_b  = (const float*)d_in[10];
  const float* w1    = (const float*)d_in[11];
  const float* b1    = (const float*)d_in[12];
  const float* w2    = (const float*)d_in[13];
  const float* b2    = (const float*)d_in[14];
  float* out = (float*)d_out;

  unsigned short* Ap = (unsigned short*)d_ws;            // 1600 x 37632 bf16-split
  unsigned short* Bp = Ap + (size_t)B_ * NBOX * KP;      // 256 x 37632
  float* tokens = (float*)(Bp + (size_t)HID * KP);       // 1600 x 256 f32

  roi_pool_kernel  <<<B_ * NBOX * 32, 64, 0, stream>>>(feat, boxes, Ap);
  wconv_kernel     <<<(HID * ROI_DIM) / 256, 256, 0, stream>>>(w_roi, Bp);
  token_init_kernel<<<(B_ * NBOX * HID) / 256, 256, 0, stream>>>(b_roi, tokens);
  gemm_kernel      <<<dim3((B_ * NBOX) / GBM, HID / GBN, KSP), 256, 0, stream>>>(Ap, Bp, tokens);
  head_kernel      <<<B_, 256, 0, stream>>>(tokens, sev_q, w_in, b_in, w_out, b_out,
                                            ln_g, ln_b, w1, b1, w2, b2, out);
}

// Round 9
// 402.457 us; speedup vs baseline: 1.1656x; 1.1656x over previous
//
#include <hip/hip_runtime.h>
#include <math.h>

#define B_    16
#define C_    256
#define H_    200
#define W_    200
#define NBOX  100
#define HID   256
#define OUTK  7
#define ROI_DIM 12544        // C_ * 49
#define KP    37632          // 3 * ROI_DIM  (split-bf16 interleave: [ah,ah,al]x[bh,bl,bh])
#define NCLS  4

struct __attribute__((packed, aligned(4))) f2u { float x, y; };

typedef __attribute__((ext_vector_type(8))) short short8v;
typedef __attribute__((ext_vector_type(4))) float f32x4;

static __device__ __forceinline__ unsigned short f2bf(float f) {
  unsigned u = __float_as_uint(f);
  return (unsigned short)((u + 0x7FFFu + ((u >> 16) & 1u)) >> 16);   // RNE
}
static __device__ __forceinline__ float bf2f(unsigned short h) {
  return __uint_as_float(((unsigned)h) << 16);
}

static __device__ __forceinline__ void gload_lds4(const void* g, void* l) {
  __builtin_amdgcn_global_load_lds(
      (const __attribute__((address_space(1))) unsigned*)g,
      (__attribute__((address_space(3))) unsigned*)l, 4, 0, 0);
}

// ---------------------------------------------------------------- K1: ROI align — two-box stream interleave, async LDS-DMA
// Block = 1 wave = (box pair, 8-channel group). Streams P(box0)/Q(box1) each
// own one 28x66 buffer; phases alternate issueQ(n) -> compute P(n) ->
// issueP(n+1) -> compute Q(n), so each stream's DMA has a full other-stream
// phase between issue and wait (~2x R7 distance) with the SAME LDS footprint
// (10 blocks/CU). Counted vmcnt(28); R7's read->lgkmcnt->sched_barrier->issue
// hazard fence kept verbatim.
__global__ __launch_bounds__(64) void roi_pool_kernel(
    const float* __restrict__ feat, const float* __restrict__ boxes,
    unsigned short* __restrict__ Ap)
{
  constexpr int SPP = 66;
  __shared__ float tileP[28][SPP], tileQ[28][SPP];   // 2 x 7.4 KB
  __shared__ int   rowoff_s[2][28];
  __shared__ int   ixs_s[2][14];
  __shared__ float flys_s[2][14], flxs_s[2][14];

  int raw = blockIdx.x;
  int g   = raw & 31;           // channel group [g*8, g*8+8); g%8 == XCD slot
  int pr  = raw >> 5;           // 0..799 box pair
  int bn0 = pr * 2;
  int b   = bn0 / NBOX;         // both boxes in same image (100 even)

  int lane = threadIdx.x;
  {   // table setup: 4 lane-groups do (box0-y, box0-x, box1-y, box1-x)
    int grp = lane >> 4, t = lane & 15;
    if (t < 14) {
      int bi = grp >> 1;
      const float* bx = boxes + (size_t)(bn0 + bi) * 4;
      if ((grp & 1) == 0) {      // y-table
        float y1 = bx[1] - 0.5f, y2 = bx[3] - 0.5f;
        float bh = (y2 - y1) * (1.0f / OUTK);
        int i = t >> 1, s = t & 1;
        float yy = y1 + ((float)i + ((float)s + 0.5f) * 0.5f) * bh;
        float yc = fminf(fmaxf(yy, 0.0f), (float)(H_ - 1));
        int y0 = min((int)floorf(yc), H_ - 2);
        rowoff_s[bi][2 * t]     = y0 * W_;
        rowoff_s[bi][2 * t + 1] = y0 * W_ + W_;
        flys_s[bi][t] = yc - (float)y0;
      } else {                   // x-table
        float x1 = bx[0] - 0.5f, x2 = bx[2] - 0.5f;
        float bw = (x2 - x1) * (1.0f / OUTK);
        int j = t >> 1, s = t & 1;
        float xx = x1 + ((float)j + ((float)s + 0.5f) * 0.5f) * bw;
        float xc = fminf(fmaxf(xx, 0.0f), (float)(W_ - 1));
        int x0 = min((int)floorf(xc), W_ - 2);
        ixs_s[bi][t]  = x0;
        flxs_s[bi][t] = xc - (float)x0;
      }
    }
  }
  asm volatile("s_waitcnt lgkmcnt(0)" ::: "memory");   // same-wave table visibility

  int xloP = ixs_s[0][0], spanP = ixs_s[0][13] + 2 - xloP;   // <= 64
  int xloQ = ixs_s[1][0], spanQ = ixs_s[1][13] + 2 - xloQ;
  bool ldP = lane < spanP, ldQ = lane < spanQ;

  int voffP[28], voffQ[28];            // per-lane global byte offsets
  #pragma unroll
  for (int r = 0; r < 28; ++r) {
    voffP[r] = (rowoff_s[0][r] + xloP + lane) * 4;
    voffQ[r] = (rowoff_s[1][r] + xloQ + lane) * 4;
  }

  // per-lane bin constants (lane = bin for lanes 0..48), both boxes
  int l49 = lane < 49 ? lane : 0;
  int bi = l49 / 7, bj = l49 - bi * 7;
  int r0 = 4 * bi;
  float lyP0 = flys_s[0][2*bi],   hyP0 = 1.0f - lyP0;
  float lyP1 = flys_s[0][2*bi+1], hyP1 = 1.0f - lyP1;
  float lxP0 = flxs_s[0][2*bj],   hxP0 = 1.0f - lxP0;
  float lxP1 = flxs_s[0][2*bj+1], hxP1 = 1.0f - lxP1;
  int xoP0 = ixs_s[0][2*bj] - xloP, xoP1 = ixs_s[0][2*bj+1] - xloP;
  float lyQ0 = flys_s[1][2*bi],   hyQ0 = 1.0f - lyQ0;
  float lyQ1 = flys_s[1][2*bi+1], hyQ1 = 1.0f - lyQ1;
  float lxQ0 = flxs_s[1][2*bj],   hxQ0 = 1.0f - lxQ0;
  float lxQ1 = flxs_s[1][2*bj+1], hxQ1 = 1.0f - lxQ1;
  int xoQ0 = ixs_s[1][2*bj] - xloQ, xoQ1 = ixs_s[1][2*bj+1] - xloQ;

  int c0 = g * 8;
  const char* fc = (const char*)(feat + (size_t)b * (C_ * H_ * W_) + (size_t)c0 * (H_ * W_));
  unsigned short* pwP = Ap + (size_t)bn0 * KP + (size_t)(c0 * 49 + l49) * 3;
  unsigned short* pwQ = Ap + (size_t)(bn0 + 1) * KP + (size_t)(c0 * 49 + l49) * 3;

  auto issueP = [&](int n) {
    const char* cb = fc + (size_t)n * (H_ * W_ * 4);
    if (ldP) {
      #pragma unroll
      for (int r = 0; r < 28; ++r) gload_lds4(cb + voffP[r], &tileP[r][0]);
    }
  };
  auto issueQ = [&](int n) {
    const char* cb = fc + (size_t)n * (H_ * W_ * 4);
    if (ldQ) {
      #pragma unroll
      for (int r = 0; r < 28; ++r) gload_lds4(cb + voffQ[r], &tileQ[r][0]);
    }
  };

  issueP(0);                           // prologue

  #pragma unroll 1
  for (int n = 0; n < 8; ++n) {
    issueQ(n);
    asm volatile("s_waitcnt vmcnt(28)" ::: "memory");   // P(n) landed
    __builtin_amdgcn_sched_barrier(0);
    f2u a0, a1, b0, b1, c2, c3, d2, d3;
    a0 = *(const f2u*)&tileP[r0 + 0][xoP0];
    a1 = *(const f2u*)&tileP[r0 + 1][xoP0];
    b0 = *(const f2u*)&tileP[r0 + 0][xoP1];
    b1 = *(const f2u*)&tileP[r0 + 1][xoP1];
    c2 = *(const f2u*)&tileP[r0 + 2][xoP0];
    c3 = *(const f2u*)&tileP[r0 + 3][xoP0];
    d2 = *(const f2u*)&tileP[r0 + 2][xoP1];
    d3 = *(const f2u*)&tileP[r0 + 3][xoP1];
    asm volatile("s_waitcnt lgkmcnt(0)" ::: "memory");  // reads in regs before overwrite
    __builtin_amdgcn_sched_barrier(0);
    if (n < 7) issueP(n + 1);
    {
      float sum = hyP0 * (hxP0 * a0.x + lxP0 * a0.y) + lyP0 * (hxP0 * a1.x + lxP0 * a1.y)
                + hyP0 * (hxP1 * b0.x + lxP1 * b0.y) + lyP0 * (hxP1 * b1.x + lxP1 * b1.y)
                + hyP1 * (hxP0 * c2.x + lxP0 * c2.y) + lyP1 * (hxP0 * c3.x + lxP0 * c3.y)
                + hyP1 * (hxP1 * d2.x + lxP1 * d2.y) + lyP1 * (hxP1 * d3.x + lxP1 * d3.y);
      if (lane < 49) {
        float s = sum * 0.25f;
        unsigned short hi = f2bf(s);
        unsigned short lo = f2bf(s - bf2f(hi));
        pwP[0] = hi; pwP[1] = hi; pwP[2] = lo;
      }
      pwP += 49 * 3;
    }
    if (n < 7) asm volatile("s_waitcnt vmcnt(28)" ::: "memory");  // Q(n) landed
    else       asm volatile("s_waitcnt vmcnt(0)"  ::: "memory");
    __builtin_amdgcn_sched_barrier(0);
    a0 = *(const f2u*)&tileQ[r0 + 0][xoQ0];
    a1 = *(const f2u*)&tileQ[r0 + 1][xoQ0];
    b0 = *(const f2u*)&tileQ[r0 + 0][xoQ1];
    b1 = *(const f2u*)&tileQ[r0 + 1][xoQ1];
    c2 = *(const f2u*)&tileQ[r0 + 2][xoQ0];
    c3 = *(const f2u*)&tileQ[r0 + 3][xoQ0];
    d2 = *(const f2u*)&tileQ[r0 + 2][xoQ1];
    d3 = *(const f2u*)&tileQ[r0 + 3][xoQ1];
    asm volatile("s_waitcnt lgkmcnt(0)" ::: "memory");
    __builtin_amdgcn_sched_barrier(0);
    {
      float sum = hyQ0 * (hxQ0 * a0.x + lxQ0 * a0.y) + lyQ0 * (hxQ0 * a1.x + lxQ0 * a1.y)
                + hyQ0 * (hxQ1 * b0.x + lxQ1 * b0.y) + lyQ0 * (hxQ1 * b1.x + lxQ1 * b1.y)
                + hyQ1 * (hxQ0 * c2.x + lxQ0 * c2.y) + lyQ1 * (hxQ0 * c3.x + lxQ0 * c3.y)
                + hyQ1 * (hxQ1 * d2.x + lxQ1 * d2.y) + lyQ1 * (hxQ1 * d3.x + lxQ1 * d3.y);
      if (lane < 49) {
        float s = sum * 0.25f;
        unsigned short hi = f2bf(s);
        unsigned short lo = f2bf(s - bf2f(hi));
        pwQ[0] = hi; pwQ[1] = hi; pwQ[2] = lo;
      }
      pwQ += 49 * 3;
    }
  }
}

// ---------------------------------------------------------------- K1b: w_roi -> split-bf16 B' [bh, bl, bh]
__global__ __launch_bounds__(256) void wconv_kernel(
    const float* __restrict__ w, unsigned short* __restrict__ Bp)
{
  int i = blockIdx.x * 256 + threadIdx.x;     // over 256*12544
  int n = i / ROI_DIM, k = i - n * ROI_DIM;
  float f = w[i];
  unsigned short hi = f2bf(f);
  unsigned short lo = f2bf(f - bf2f(hi));
  unsigned short* r = Bp + (size_t)n * KP + 3 * k;
  r[0] = hi; r[1] = lo; r[2] = hi;
}

// ---------------------------------------------------------------- K2: token init (bias)
__global__ __launch_bounds__(256) void token_init_kernel(
    const float* __restrict__ b_roi, float* __restrict__ tokens)
{
  int i = blockIdx.x * 256 + threadIdx.x;   // 409600 total
  tokens[i] = b_roi[i & 255];
}

// ---------------------------------------------------------------- K3: bf16 MFMA GEMM  tokens += A'(1600xKP) @ B'(256xKP)^T
#define GBM 64
#define GBN 128
#define GBK 64
#define KSP 28
#define KT  21        // (KP/GBK)/KSP = 588/28
__global__ __launch_bounds__(256) void gemm_kernel(
    const unsigned short* __restrict__ Ap,
    const unsigned short* __restrict__ Bp,
    float* __restrict__ Cc)
{
  __shared__ __align__(16) short As[GBM * GBK];   // [row][8 chunks x 8 bf16], swizzled
  __shared__ __align__(16) short Bs[GBN * GBK];

  int tid  = threadIdx.x;
  int lane = tid & 63;
  int w    = tid >> 6;
  int wr   = w >> 1, wc = w & 1;          // wave (wr,wc): rows wr*32, cols wc*64
  int m0 = blockIdx.x * GBM;
  int n0 = blockIdx.y * GBN;
  int kbase = blockIdx.z * (GBK * KT);

  f32x4 acc[2][4];
  #pragma unroll
  for (int mi = 0; mi < 2; ++mi)
    #pragma unroll
    for (int nj = 0; nj < 4; ++nj)
      acc[mi][nj] = (f32x4){0.f, 0.f, 0.f, 0.f};

  for (int kt = 0; kt < KT; ++kt) {
    int kg = kbase + kt * GBK;
    __syncthreads();                       // previous compute done before overwrite
    #pragma unroll
    for (int r = 0; r < 2; ++r) {          // stage A: 512 chunks of 16B
      int q = tid + r * 256;
      int row = q >> 3, c16 = q & 7;
      int kc16 = c16 ^ (row & 7);
      short8v v = *(const short8v*)(Ap + (size_t)(m0 + row) * KP + kg + kc16 * 8);
      *(short8v*)(As + row * GBK + c16 * 8) = v;
    }
    #pragma unroll
    for (int r = 0; r < 4; ++r) {          // stage B: 1024 chunks
      int q = tid + r * 256;
      int row = q >> 3, c16 = q & 7;
      int kc16 = c16 ^ (row & 7);
      short8v v = *(const short8v*)(Bp + (size_t)(n0 + row) * KP + kg + kc16 * 8);
      *(short8v*)(Bs + row * GBK + c16 * 8) = v;
    }
    __syncthreads();
    #pragma unroll
    for (int kk = 0; kk < 2; ++kk) {       // two K=32 steps per tile
      short8v af[2], bf[4];
      #pragma unroll
      for (int mi = 0; mi < 2; ++mi) {
        int row = wr * 32 + mi * 16 + (lane & 15);
        int c16 = (kk * 4 + (lane >> 4)) ^ (row & 7);
        af[mi] = *(const short8v*)(As + row * GBK + c16 * 8);
      }
      #pragma unroll
      for (int nj = 0; nj < 4; ++nj) {
        int row = wc * 64 + nj * 16 + (lane & 15);
        int c16 = (kk * 4 + (lane >> 4)) ^ (row & 7);
        bf[nj] = *(const short8v*)(Bs + row * GBK + c16 * 8);
      }
      #pragma unroll
      for (int mi = 0; mi < 2; ++mi)
        #pragma unroll
        for (int nj = 0; nj < 4; ++nj)
          acc[mi][nj] = __builtin_amdgcn_mfma_f32_16x16x32_bf16(
              af[mi], bf[nj], acc[mi][nj], 0, 0, 0);
    }
  }
  // epilogue: D col = lane&15, row = (lane>>4)*4 + reg
  int cn = lane & 15, rg = lane >> 4;
  #pragma unroll
  for (int mi = 0; mi < 2; ++mi)
    #pragma unroll
    for (int nj = 0; nj < 4; ++nj)
      #pragma unroll
      for (int r = 0; r < 4; ++r) {
        int row = m0 + wr * 32 + mi * 16 + rg * 4 + r;
        int col = n0 + wc * 64 + nj * 16 + cn;
        atomicAdd(&Cc[(size_t)row * HID + col], acc[mi][nj][r]);
      }
}

// ---------------------------------------------------------------- K4: attention + LN + MLP (one block per batch)
__global__ __launch_bounds__(256) void head_kernel(
    const float* __restrict__ tokens, const float* __restrict__ sev_q,
    const float* __restrict__ w_in,  const float* __restrict__ b_in,
    const float* __restrict__ w_out, const float* __restrict__ b_out,
    const float* __restrict__ ln_g,  const float* __restrict__ ln_b,
    const float* __restrict__ w1,    const float* __restrict__ b1,
    const float* __restrict__ w2,    const float* __restrict__ b2,
    float* __restrict__ outp)
{
  __shared__ float qh_s[256], qkv_s[1024], qkb_s[4];
  __shared__ float sc_s[400], att_s[400], tbar_s[1024];
  __shared__ float ctx_s[256], o_s[256], x_s[256], h1_s[256], red_s[8];
  int b = blockIdx.x, tid = threadIdx.x;
  const float* tok = tokens + (size_t)b * NBOX * HID;

  {
    const float* wq = w_in + (size_t)tid * HID;
    float a = 0.0f;
    for (int e = 0; e < HID; ++e) a += sev_q[e] * wq[e];
    qh_s[tid] = a + b_in[tid];
  }
  __syncthreads();
  if (tid < 4) {
    float a = 0.0f;
    for (int d = 0; d < 64; ++d) a += qh_s[tid * 64 + d] * b_in[256 + tid * 64 + d];
    qkb_s[tid] = a;
  }
  #pragma unroll
  for (int r = 0; r < 4; ++r) {
    int p = tid + r * 256;
    int h = p >> 8, e = p & 255;
    float a = 0.0f;
    for (int d = 0; d < 64; ++d)
      a += qh_s[h * 64 + d] * w_in[(size_t)(256 + h * 64 + d) * HID + e];
    qkv_s[p] = a;
  }
  __syncthreads();
  for (int p = tid; p < 4 * NBOX; p += 256) {
    int h = p / NBOX, t = p - h * NBOX;
    const float* tr = tok + (size_t)t * HID;
    const float* qv = qkv_s + h * 256;
    float a = 0.0f;
    for (int e = 0; e < HID; ++e) a += qv[e] * tr[e];
    sc_s[p] = (a + qkb_s[h]) * 0.125f;
  }
  __syncthreads();
  if (tid < 4) {
    float mx = -1e30f;
    for (int t = 0; t < NBOX; ++t) mx = fmaxf(mx, sc_s[tid * NBOX + t]);
    float sm = 0.0f;
    for (int t = 0; t < NBOX; ++t) {
      float e = expf(sc_s[tid * NBOX + t] - mx);
      att_s[tid * NBOX + t] = e; sm += e;
    }
    float inv = 1.0f / sm;
    for (int t = 0; t < NBOX; ++t) att_s[tid * NBOX + t] *= inv;
  }
  __syncthreads();
  #pragma unroll
  for (int r = 0; r < 4; ++r) {
    int p = tid + r * 256;
    int h = p >> 8, e = p & 255;
    float a = 0.0f;
    for (int t = 0; t < NBOX; ++t) a += att_s[h * NBOX + t] * tok[(size_t)t * HID + e];
    tbar_s[p] = a;
  }
  __syncthreads();
  {
    int h = tid >> 6;
    const float* wv = w_in + (size_t)(512 + tid) * HID;
    const float* tb = tbar_s + h * 256;
    float a = 0.0f;
    for (int e = 0; e < HID; ++e) a += tb[e] * wv[e];
    ctx_s[tid] = a + b_in[512 + tid];
  }
  __syncthreads();
  {
    const float* wo = w_out + (size_t)tid * HID;
    float a = 0.0f;
    for (int k = 0; k < HID; ++k) a += ctx_s[k] * wo[k];
    o_s[tid] = a + b_out[tid];
  }
  __syncthreads();
  {
    float v = o_s[tid];
    float s1 = v, s2 = v * v;
    #pragma unroll
    for (int off = 32; off > 0; off >>= 1) {
      s1 += __shfl_down(s1, off);
      s2 += __shfl_down(s2, off);
    }
    if ((tid & 63) == 0) { red_s[(tid >> 6) * 2] = s1; red_s[(tid >> 6) * 2 + 1] = s2; }
    __syncthreads();
    float sum = red_s[0] + red_s[2] + red_s[4] + red_s[6];
    float ssq = red_s[1] + red_s[3] + red_s[5] + red_s[7];
    float mu  = sum * (1.0f / 256.0f);
    float var = ssq * (1.0f / 256.0f) - mu * mu;
    float inv = rsqrtf(var + 1e-5f);
    x_s[tid] = (v - mu) * inv * ln_g[tid] + ln_b[tid];
  }
  __syncthreads();
  {
    const float* wr = w1 + (size_t)tid * HID;
    float a = 0.0f;
    for (int k = 0; k < HID; ++k) a += x_s[k] * wr[k];
    h1_s[tid] = fmaxf(a + b1[tid], 0.0f);
  }
  __syncthreads();
  if (tid < NCLS) {
    const float* wr = w2 + (size_t)tid * HID;
    float a = 0.0f;
    for (int k = 0; k < HID; ++k) a += h1_s[k] * wr[k];
    outp[b * NCLS + tid] = a + b2[tid];
  }
}

// ---------------------------------------------------------------- launch
extern "C" void kernel_launch(void* const* d_in, const int* in_sizes, int n_in,
                              void* d_out, int out_size, void* d_ws, size_t ws_size,
                              hipStream_t stream) {
  (void)in_sizes; (void)n_in; (void)out_size; (void)ws_size;
  const float* feat  = (const float*)d_in[0];
  const float* boxes = (const float*)d_in[1];
  const float* w_roi = (const float*)d_in[2];
  const float* b_roi = (const float*)d_in[3];
  const float* sev_q = (const float*)d_in[4];
  const float* w_in  = (const float*)d_in[5];
  const float* b_in  = (const float*)d_in[6];
  const float* w_out = (const float*)d_in[7];
  const float* b_out = (const float*)d_in[8];
  const float* ln_g  = (const float*)d_in[9];
  const float* ln_b  = (const float*)d_in[10];
  const float* w1    = (const float*)d_in[11];
  const float* b1    = (const float*)d_in[12];
  const float* w2    = (const float*)d_in[13];
  const float* b2    = (const float*)d_in[14];
  float* out = (float*)d_out;

  unsigned short* Ap = (unsigned short*)d_ws;            // 1600 x 37632 bf16-split
  unsigned short* Bp = Ap + (size_t)B_ * NBOX * KP;      // 256 x 37632
  float* tokens = (float*)(Bp + (size_t)HID * KP);       // 1600 x 256 f32

  roi_pool_kernel  <<<(B_ * NBOX / 2) * 32, 64, 0, stream>>>(feat, boxes, Ap);
  wconv_kernel     <<<(HID * ROI_DIM) / 256, 256, 0, stream>>>(w_roi, Bp);
  token_init_kernel<<<(B_ * NBOX * HID) / 256, 256, 0, stream>>>(b_roi, tokens);
  gemm_kernel      <<<dim3((B_ * NBOX) / GBM, HID / GBN, KSP), 256, 0, stream>>>(Ap, Bp, tokens);
  head_kernel      <<<B_, 256, 0, stream>>>(tokens, sev_q, w_in, b_in, w_out, b_out,
                                            ln_g, ln_b, w1, b1, w2, b2, out);
}